// Round 1
// baseline (18694.209 us; speedup 1.0000x reference)
//
#include <hip/hip_runtime.h>
#include <math.h>

// Model dims (fixed by the reference)
#define Lc   6
#define Dc   1024
#define FFc  4096
#define Vc   32000
#define Bc   2
#define Sc   1024
#define Hc   16
#define GSc  128
#define DHc  64
#define Mc   (Bc * Sc)   // 2048 token rows

// ---------------------------------------------------------------------------
// Block-wide reductions (256 threads = 4 waves of 64)
// ---------------------------------------------------------------------------
__device__ inline float block_reduce_sum(float v, float* scratch) {
    __syncthreads();  // protect scratch from previous use
    int lane = threadIdx.x & 63, w = threadIdx.x >> 6;
#pragma unroll
    for (int off = 32; off > 0; off >>= 1) v += __shfl_down(v, off, 64);
    if (lane == 0) scratch[w] = v;
    __syncthreads();
    if (threadIdx.x == 0) scratch[0] = scratch[0] + scratch[1] + scratch[2] + scratch[3];
    __syncthreads();
    return scratch[0];
}

__device__ inline float block_reduce_max(float v, float* scratch) {
    __syncthreads();
    int lane = threadIdx.x & 63, w = threadIdx.x >> 6;
#pragma unroll
    for (int off = 32; off > 0; off >>= 1) v = fmaxf(v, __shfl_down(v, off, 64));
    if (lane == 0) scratch[w] = v;
    __syncthreads();
    if (threadIdx.x == 0)
        scratch[0] = fmaxf(fmaxf(scratch[0], scratch[1]), fmaxf(scratch[2], scratch[3]));
    __syncthreads();
    return scratch[0];
}

// ---------------------------------------------------------------------------
// Embedding gather + dequant + pos add.  grid = Mc blocks, 256 thr.
// x[row,d] = emb_t[idx,d] * emb_s[(idx*D+d)/GS] + pos[row%S, d]
// ---------------------------------------------------------------------------
__global__ __launch_bounds__(256) void k_embed(const int* __restrict__ ids,
                                               const float* __restrict__ et,
                                               const float* __restrict__ es,
                                               const float* __restrict__ pos,
                                               float* __restrict__ x) {
    int row = blockIdx.x;
    int sp  = row & (Sc - 1);
    int d   = threadIdx.x << 2;
    int idx = ids[row];
    int base = idx * Dc + d;
    float4 t = *(const float4*)(et + base);
    float  s = es[base >> 7];          // GS=128 groups along flat (v*D+d)
    float4 p = *(const float4*)(pos + sp * Dc + d);
    float4 o;
    o.x = fmaf(t.x, s, p.x); o.y = fmaf(t.y, s, p.y);
    o.z = fmaf(t.z, s, p.z); o.w = fmaf(t.w, s, p.w);
    *(float4*)(x + row * Dc + d) = o;
}

// ---------------------------------------------------------------------------
// RMSNorm: one block per row (D=1024, 256 thr * float4)
// ---------------------------------------------------------------------------
__global__ __launch_bounds__(256) void k_rmsnorm(const float* __restrict__ x,
                                                 const float* __restrict__ w,
                                                 float* __restrict__ o) {
    __shared__ float scratch[4];
    int row = blockIdx.x;
    int d = threadIdx.x << 2;
    float4 f = *(const float4*)(x + row * Dc + d);
    float s = f.x * f.x + f.y * f.y + f.z * f.z + f.w * f.w;
    s = block_reduce_sum(s, scratch);
    float rinv = rsqrtf(s * (1.0f / Dc) + 1e-6f);
    float4 wv = *(const float4*)(w + d);
    float4 out;
    out.x = f.x * rinv * wv.x; out.y = f.y * rinv * wv.y;
    out.z = f.z * rinv * wv.z; out.w = f.w * rinv * wv.w;
    *(float4*)(o + row * Dc + d) = out;
}

// ---------------------------------------------------------------------------
// Fused-dequant GEMM:  C[M,N] = A[M,K] @ dq(Wt,Ws)[N,K]^T  (+ R residual)
// 64x64 tile, BK=16, 256 threads, 4x4 per thread.
// LDS layout [16][68]: pad 68 => store bank aliasing <=2-way (free),
// 272B row stride keeps float4 reads 16B-aligned.
// All dims here are multiples of 64 (M=2048, N in {1024,4096,32000}), K%16==0.
// ---------------------------------------------------------------------------
template <bool RESID>
__global__ __launch_bounds__(256) void k_gemm_dq(const float* __restrict__ A,
                                                 const float* __restrict__ Wt,
                                                 const float* __restrict__ Ws,
                                                 const float* __restrict__ R,
                                                 float* __restrict__ C,
                                                 int N, int K) {
    __shared__ float As[16][68];
    __shared__ float Bs[16][68];
    const int bm = blockIdx.y << 6, bn = blockIdx.x << 6;
    const int tid = threadIdx.x;
    const int tx = tid & 15, ty = tid >> 4;
    const int kg = K >> 7;  // groups per weight row
    float acc[4][4] = {};

    for (int k0 = 0; k0 < K; k0 += 16) {
        const int gidx = k0 >> 7;  // BK=16 never straddles a GS=128 boundary
#pragma unroll
        for (int i = 0; i < 4; ++i) {
            int flat = tid + (i << 8);
            int r = flat >> 4, kk = flat & 15;
            As[kk][r] = A[(bm + r) * K + k0 + kk];
            int n = bn + r;
            Bs[kk][r] = Wt[n * K + k0 + kk] * Ws[n * kg + gidx];
        }
        __syncthreads();
#pragma unroll
        for (int kk = 0; kk < 16; ++kk) {
            float4 a = *(const float4*)&As[kk][ty << 2];
            float4 b = *(const float4*)&Bs[kk][tx << 2];
            float av[4] = {a.x, a.y, a.z, a.w};
            float bv[4] = {b.x, b.y, b.z, b.w};
#pragma unroll
            for (int i = 0; i < 4; ++i)
#pragma unroll
                for (int j = 0; j < 4; ++j)
                    acc[i][j] = fmaf(av[i], bv[j], acc[i][j]);
        }
        __syncthreads();
    }

#pragma unroll
    for (int i = 0; i < 4; ++i) {
        int m = bm + (ty << 2) + i;
        int off = m * N + bn + (tx << 2);
        float4 v = make_float4(acc[i][0], acc[i][1], acc[i][2], acc[i][3]);
        if (RESID) {
            float4 r = *(const float4*)(R + off);
            v.x += r.x; v.y += r.y; v.z += r.z; v.w += r.w;
        }
        *(float4*)(C + off) = v;
    }
}

// ---------------------------------------------------------------------------
// Fused gate/up GEMM + SiLU:  O = silu(A@G^T) * (A@U^T).  N=FF, K=D.
// ---------------------------------------------------------------------------
__global__ __launch_bounds__(256) void k_gateup(const float* __restrict__ A,
                                                const float* __restrict__ Gt,
                                                const float* __restrict__ Gsc,
                                                const float* __restrict__ Ut,
                                                const float* __restrict__ Usc,
                                                float* __restrict__ O) {
    __shared__ float As[16][68];
    __shared__ float Bg[16][68];
    __shared__ float Bu[16][68];
    const int bm = blockIdx.y << 6, bn = blockIdx.x << 6;
    const int tid = threadIdx.x;
    const int tx = tid & 15, ty = tid >> 4;
    const int K = Dc, kg = Dc >> 7;  // 8
    float ag[4][4] = {};
    float au[4][4] = {};

    for (int k0 = 0; k0 < K; k0 += 16) {
        const int gidx = k0 >> 7;
#pragma unroll
        for (int i = 0; i < 4; ++i) {
            int flat = tid + (i << 8);
            int r = flat >> 4, kk = flat & 15;
            As[kk][r] = A[(bm + r) * K + k0 + kk];
            int n = bn + r;
            float gs = Gsc[n * kg + gidx], us = Usc[n * kg + gidx];
            Bg[kk][r] = Gt[n * K + k0 + kk] * gs;
            Bu[kk][r] = Ut[n * K + k0 + kk] * us;
        }
        __syncthreads();
#pragma unroll
        for (int kk = 0; kk < 16; ++kk) {
            float4 a  = *(const float4*)&As[kk][ty << 2];
            float4 g4 = *(const float4*)&Bg[kk][tx << 2];
            float4 u4 = *(const float4*)&Bu[kk][tx << 2];
            float av[4] = {a.x, a.y, a.z, a.w};
            float gv[4] = {g4.x, g4.y, g4.z, g4.w};
            float uv[4] = {u4.x, u4.y, u4.z, u4.w};
#pragma unroll
            for (int i = 0; i < 4; ++i)
#pragma unroll
                for (int j = 0; j < 4; ++j) {
                    ag[i][j] = fmaf(av[i], gv[j], ag[i][j]);
                    au[i][j] = fmaf(av[i], uv[j], au[i][j]);
                }
        }
        __syncthreads();
    }

#pragma unroll
    for (int i = 0; i < 4; ++i) {
        int m = bm + (ty << 2) + i;
        int off = m * FFc + bn + (tx << 2);
        float4 v;
        float* vp = &v.x;
#pragma unroll
        for (int j = 0; j < 4; ++j) {
            float g = ag[i][j], u = au[i][j];
            float si = g / (1.0f + expf(-g));  // silu
            vp[j] = si * u;
        }
        *(float4*)(O + off) = v;
    }
}

// ---------------------------------------------------------------------------
// Attention: one block per (q-row, head, batch). grid = (S, H, B), 256 thr.
// Scores for keys 0..qi in LDS, two-pass softmax, PV accumulate,
// fused residual head-mix: out += alpha[h] * h_normed.
// ---------------------------------------------------------------------------
__global__ __launch_bounds__(256) void k_attn(const float* __restrict__ q,
                                              const float* __restrict__ k,
                                              const float* __restrict__ v,
                                              const float* __restrict__ hn,
                                              const float* __restrict__ alpha,
                                              float* __restrict__ out) {
    __shared__ float qs[DHc];
    __shared__ float sc[Sc];
    __shared__ float red[256];
    __shared__ float scratch[4];
    const int qi = blockIdx.x, hh = blockIdx.y, b = blockIdx.z;
    const int tid = threadIdx.x;
    const int rowbase = (b * Sc + qi) * Dc + hh * DHc;

    if (tid < DHc) qs[tid] = q[rowbase + tid];
    __syncthreads();

    const int nk = qi + 1;
    const float* kb = k + b * Sc * Dc + hh * DHc;
    for (int j = tid; j < nk; j += 256) {
        const float4* kr = (const float4*)(kb + j * Dc);
        float dot = 0.0f;
#pragma unroll
        for (int t = 0; t < 16; ++t) {
            float4 kv = kr[t];
            dot += qs[4 * t] * kv.x + qs[4 * t + 1] * kv.y +
                   qs[4 * t + 2] * kv.z + qs[4 * t + 3] * kv.w;
        }
        sc[j] = dot * 0.125f;  // DH^-0.5
    }
    // each thread only re-reads its own sc[] entries for the local max
    float mx = -3.0e38f;
    for (int j = tid; j < nk; j += 256) mx = fmaxf(mx, sc[j]);
    mx = block_reduce_max(mx, scratch);

    float ss = 0.0f;
    for (int j = tid; j < nk; j += 256) {
        float e = expf(sc[j] - mx);
        sc[j] = e;
        ss += e;
    }
    ss = block_reduce_sum(ss, scratch);
    float inv = 1.0f / ss;
    __syncthreads();  // sc[] now fully written; pass 2 reads all of it

    const int dh = tid & 63, g = tid >> 6;
    const float* vb = v + b * Sc * Dc + hh * DHc + dh;
    float acc = 0.0f;
    for (int j = g; j < nk; j += 4) acc = fmaf(sc[j], vb[j * Dc], acc);
    red[tid] = acc;
    __syncthreads();
    if (tid < 64) {
        float r = (red[tid] + red[tid + 64] + red[tid + 128] + red[tid + 192]) * inv;
        int oidx = rowbase + tid;
        out[oidx] = fmaf(alpha[hh], hn[oidx], r);
    }
}

// ---------------------------------------------------------------------------
// Launcher
// ---------------------------------------------------------------------------
extern "C" void kernel_launch(void* const* d_in, const int* in_sizes, int n_in,
                              void* d_out, int out_size, void* d_ws, size_t ws_size,
                              hipStream_t stream) {
    const int*   ids    = (const int*)d_in[0];
    const float* emb_t  = (const float*)d_in[1];
    const float* emb_s  = (const float*)d_in[2];
    const float* pos    = (const float*)d_in[3];
    const float* q_t    = (const float*)d_in[4];
    const float* q_s    = (const float*)d_in[5];
    const float* k_t    = (const float*)d_in[6];
    const float* k_s    = (const float*)d_in[7];
    const float* v_t    = (const float*)d_in[8];
    const float* v_s    = (const float*)d_in[9];
    const float* o_t    = (const float*)d_in[10];
    const float* o_s    = (const float*)d_in[11];
    const float* g_t    = (const float*)d_in[12];
    const float* g_s    = (const float*)d_in[13];
    const float* u_t    = (const float*)d_in[14];
    const float* u_s    = (const float*)d_in[15];
    const float* dd_t   = (const float*)d_in[16];
    const float* dd_s   = (const float*)d_in[17];
    const float* alpha  = (const float*)d_in[18];
    const float* na_w   = (const float*)d_in[19];
    const float* nm_w   = (const float*)d_in[20];
    const float* nf_w   = (const float*)d_in[21];
    const float* head_t = (const float*)d_in[22];
    const float* head_s = (const float*)d_in[23];
    float* outp = (float*)d_out;

    // Workspace layout (floats):
    //   x   : Mc*Dc        (2.10M)
    //   h   : Mc*Dc        (2.10M)
    //   big : Mc*FFc       (8.39M) = q|k|v|attout during attention, ff during MLP
    float* ws  = (float*)d_ws;
    float* x   = ws;
    float* h   = x + (size_t)Mc * Dc;
    float* big = h + (size_t)Mc * Dc;
    float* qb  = big;
    float* kb  = big + (size_t)Mc * Dc;
    float* vb  = big + (size_t)2 * Mc * Dc;
    float* ao  = big + (size_t)3 * Mc * Dc;
    float* ff  = big;  // reuse: q/k/v/ao dead once o-proj is done

    k_embed<<<Mc, 256, 0, stream>>>(ids, emb_t, emb_s, pos, x);

    const dim3 gD(Dc / 64, Mc / 64);    // N=1024
    const dim3 gF(FFc / 64, Mc / 64);   // N=4096
    const dim3 gA(Sc, Hc, Bc);
    for (int l = 0; l < Lc; ++l) {
        const float* qt = q_t + (size_t)l * Dc * Dc;
        const float* qs = q_s + (size_t)l * (Dc * Dc / GSc);
        const float* kt = k_t + (size_t)l * Dc * Dc;
        const float* ks = k_s + (size_t)l * (Dc * Dc / GSc);
        const float* vt = v_t + (size_t)l * Dc * Dc;
        const float* vs = v_s + (size_t)l * (Dc * Dc / GSc);
        const float* ot = o_t + (size_t)l * Dc * Dc;
        const float* os = o_s + (size_t)l * (Dc * Dc / GSc);
        const float* gt = g_t + (size_t)l * FFc * Dc;
        const float* gs = g_s + (size_t)l * (FFc * Dc / GSc);
        const float* ut = u_t + (size_t)l * FFc * Dc;
        const float* us = u_s + (size_t)l * (FFc * Dc / GSc);
        const float* dt = dd_t + (size_t)l * Dc * FFc;
        const float* ds = dd_s + (size_t)l * (Dc * FFc / GSc);

        k_rmsnorm<<<Mc, 256, 0, stream>>>(x, na_w + l * Dc, h);
        k_gemm_dq<false><<<gD, 256, 0, stream>>>(h, qt, qs, nullptr, qb, Dc, Dc);
        k_gemm_dq<false><<<gD, 256, 0, stream>>>(h, kt, ks, nullptr, kb, Dc, Dc);
        k_gemm_dq<false><<<gD, 256, 0, stream>>>(h, vt, vs, nullptr, vb, Dc, Dc);
        k_attn<<<gA, 256, 0, stream>>>(qb, kb, vb, h, alpha + l * Hc, ao);
        k_gemm_dq<true><<<gD, 256, 0, stream>>>(ao, ot, os, x, x, Dc, Dc);
        k_rmsnorm<<<Mc, 256, 0, stream>>>(x, nm_w + l * Dc, h);
        k_gateup<<<gF, 256, 0, stream>>>(h, gt, gs, ut, us, ff);
        k_gemm_dq<true><<<gD, 256, 0, stream>>>(ff, dt, ds, x, x, Dc, FFc);
    }

    k_rmsnorm<<<Mc, 256, 0, stream>>>(x, nf_w, h);
    const dim3 gH(Vc / 64, Mc / 64);    // N=32000
    k_gemm_dq<false><<<gH, 256, 0, stream>>>(h, head_t, head_s, nullptr, outp, Vc, Dc);
}